// Round 9
// baseline (158.985 us; speedup 1.0000x reference)
//
#include <hip/hip_runtime.h>

// Fused 4x upsample (two polyphase 2x stages composed): out[t] = sum_n g[t-2-4n] x[n],
// g = f (*) up2(f), 67 taps, circular, symmetric. Phases of out col/row t mod 4:
// 0 -> 12-tap (tC6), 1 -> 17-tap (tapA), 2 -> copy, 3 -> tapA reversed.
// Round-9: VALU-issue attack. Model: ~1012 scalar v_fma_f32/thread ≈ 27us issue floor
// (matches observed ~41-45us at the ~65% practical VALU ceiling); all memory levers
// (r1 LDS vec, r5 occupancy, r8 store overlap) came back neutral -> compute-bound.
// Change vs r8: vertical-pass accumulation in packed fp32 (v2f ext-vectors ->
// v_pk_fma_f32, 2 cols/inst). V insts 736 -> ~368/thread. H stays scalar (packing
// it needs 34 tap-pair VGPRs -> spill risk). Everything else identical to r8.

#define SINS 52      // sIn row stride (48 used + 4 pad; float4-aligned)
#define SMS 132      // sMid row stride (128 + 4 pad)

typedef float v2f __attribute__((ext_vector_type(2)));

// packed fma over a float4 accumulator: 2x v_pk_fma_f32 (cols xy, zw), tap splat
__device__ __forceinline__ void pkfma2(float4& a, float t, const float4& r) {
    v2f& al = *(v2f*)&a.x;
    v2f& ah = *(v2f*)&a.z;
    const v2f rl = { r.x, r.y }, rh = { r.z, r.w };
    const v2f tt = { t, t };
    al = __builtin_elementwise_fma(rl, tt, al);
    ah = __builtin_elementwise_fma(rh, tt, ah);
}

__global__ __launch_bounds__(256, 4) void up4_fused(
    const float* __restrict__ in, const float* __restrict__ kern,
    float* __restrict__ out) {
    __shared__ float sG[80];
    __shared__ __attribute__((aligned(16))) float sMid[48][SMS];
    __shared__ __attribute__((aligned(16))) float sIn[48][SINS];

    const int tid = threadIdx.x;
    const int tX = blockIdx.x, tY = blockIdx.y, ch = blockIdx.z;

    // ---- compute g = f (*) up2(f) inline, threads 0..79: sG[u] = g[u-34] ----
    if (tid < 80) {
        const int s = tid - 34;
        int jlo = (s - 10) >> 1;        // ceil((s-11)/2)
        int jhi = (s + 11) >> 1;        // floor((s+11)/2)
        if (jlo < -11) jlo = -11;
        if (jhi > 11) jhi = 11;
        float acc = 0.f;
        for (int j = jlo; j <= jhi; ++j)
            acc += kern[11 + s - 2 * j] * kern[11 + j];
        sG[tid] = acc;
    }

    // ---- load 48x48 input patch (0-based): sIn[pi][pj] = inC[(N0y+1+pi)&255][(N0x+1+pj)&255]
    const float* inC = in + (size_t)ch * 256 * 256;
    const int N0y = 32 * tY - 9, N0x = 32 * tX - 9;
    const int gj0 = (N0x + 1) & 255;    // ≡ 0 (mod 8) -> float4-aligned
    if (gj0 <= 208) {
        // fast path: 48-col x-range contiguous (no wrap): 48 rows x 12 float4
#pragma unroll
        for (int it = 0; it < 3; ++it) {
            const int idx = tid + it * 256;         // 0..575
            if (idx < 576) {
                const int pi = idx / 12, m = idx % 12;
                const int gi = (N0y + 1 + pi + 256) & 255;
                *(float4*)&sIn[pi][4 * m] =
                    *(const float4*)&inC[gi * 256 + gj0 + 4 * m];
            }
        }
    } else {
        // wrap path (tX = 0 or 7): scalar with per-element wrap
#pragma unroll
        for (int it = 0; it < 9; ++it) {
            const int idx = tid + it * 256;         // 0..2303
            const int pi = idx / 48, pj = idx % 48;
            const int gi = (N0y + 1 + pi + 256) & 255;
            const int gj = (N0x + 1 + pj + 256) & 255;
            sIn[pi][pj] = inC[gi * 256 + gj];
        }
    }
    __syncthreads();

    // ---- taps in registers (g symmetric -> 23 regs), LDS broadcast reads ----
    float tapA[17], tC6[6];
#pragma unroll
    for (int k = 0; k < 17; ++k) tapA[k] = sG[1 + 4 * k];
#pragma unroll
    for (int m = 0; m < 6; ++m) tC6[m] = sG[12 + 4 * m];

    float* outC = out + (size_t)ch * 1024 * 1024;
    const int orow0 = 128 * tY, ocol0 = 128 * tX;

    // ---- horizontal polyphase: 48 rows x 32 col-quads, 6 tasks/thread ----
    // 0-based window: quad c reads sIn[row][c .. c+16] via w = sIn[row][c+16-k].
    // Iterations 1..4 (sMid rows 8..39) double as copy-phase output rows 4*(row-8)+2:
    // store the live v straight to global (drain starts during horiz, no barrier wait).
#pragma unroll
    for (int it = 0; it < 6; ++it) {
        const int idx = tid + it * 256;             // 0..1535
        const int c = idx & 31, row = idx >> 5;
        float a0 = 0.f, a1 = 0.f, a2 = 0.f, a3 = 0.f;
#pragma unroll
        for (int k = 0; k < 17; ++k) {
            const float w = sIn[row][c + 16 - k];
            a1 += tapA[k] * w;
            a3 += tapA[16 - k] * w;
            if (k >= 3 && k <= 14) {
                const int m2 = k - 3;
                a0 += tC6[m2 < 6 ? m2 : 11 - m2] * w;
            }
            if (k == 8) a2 = w;
        }
        float4 v; v.x = a0; v.y = a1; v.z = a2; v.w = a3;
        *(float4*)&sMid[row][4 * c] = v;
        if (it >= 1 && it <= 4)                     // compile-time per iteration
            *(float4*)&outC[(size_t)(orow0 + 4 * (row - 8) + 2) * 1024 + ocol0 + 4 * c] = v;
    }
    __syncthreads();

    // ---- vertical polyphase: 4 row-groups/thread, rolling 20-row window ----
    // A[i][0]=phase0 (tC6), A[i][1]=phase1 (tapA), A[i][2]=phase3 (tapA reversed).
    // Accumulation via v_pk_fma_f32 (2 columns per instruction).
    const int c = tid & 31, gp = tid >> 5;          // c: col-quad, gp: 0..7
    float4 A[4][3];
#pragma unroll
    for (int i = 0; i < 4; ++i)
#pragma unroll
        for (int p = 0; p < 3; ++p) { A[i][p].x = 0.f; A[i][p].y = 0.f; A[i][p].z = 0.f; A[i][p].w = 0.f; }

#pragma unroll
    for (int d = 1; d <= 20; ++d) {
        const float4 R = *(const float4*)&sMid[4 * gp + d - 1][4 * c];
#pragma unroll
        for (int i = 0; i < 4; ++i) {
            const int k = i + 17 - d;               // tap index for row-group 4*gp+i
            if (k < 0 || k > 16) continue;
            pkfma2(A[i][1], tapA[k], R);
            pkfma2(A[i][2], tapA[16 - k], R);
            if (k >= 3 && k <= 14) {
                const int m = k - 3;
                pkfma2(A[i][0], tC6[m < 6 ? m : 11 - m], R);
            }
        }
    }

#pragma unroll
    for (int i = 0; i < 4; ++i) {
        const int R0 = 4 * gp + i;                  // rowgroup: out local rows 4*R0+{0,1,3}
        const size_t rbase = (size_t)(orow0 + 4 * R0) * 1024 + ocol0 + 4 * c;
        *(float4*)&outC[rbase]            = A[i][0];    // phase 0
        *(float4*)&outC[rbase + 1024]     = A[i][1];    // phase 1
        *(float4*)&outC[rbase + 3 * 1024] = A[i][2];    // phase 3
    }
}

extern "C" void kernel_launch(void* const* d_in, const int* in_sizes, int n_in,
                              void* d_out, int out_size, void* d_ws, size_t ws_size,
                              hipStream_t stream) {
    const float* x    = (const float*)d_in[0];   // (32, 256, 256)
    const float* kern = (const float*)d_in[1];   // 23 taps
    float* out  = (float*)d_out;                 // (32, 1024, 1024)

    dim3 grid(8, 8, 32);                         // 128x128 output tiles
    up4_fused<<<grid, dim3(256), 0, stream>>>(x, kern, out);
}